// Round 11
// baseline (105.032 us; speedup 1.0000x reference)
//
#include <hip/hip_runtime.h>

typedef __attribute__((ext_vector_type(8))) short short8;
typedef __attribute__((ext_vector_type(16))) float f32x16;

// d_ws layout (ushort elements):
#define WS_GT   0        // 26*8 = 208 bf16
#define WS_CT   256      // 27*8 = 216 bf16
#define WS_W1T  512      // 256 cols * 13 slots * 8 bf16 = 26624 ushorts (52 KB)
                         // slots 0-11: W1T data (s = kk*2 + hi); slot 12: (b1,0,..,0)

__device__ __forceinline__ unsigned short f2bf(float f) {
    unsigned int u = __float_as_uint(f);
    u = (u + 0x7fffu + ((u >> 16) & 1u)) >> 16;   // RNE
    return (unsigned short)u;
}
__device__ __forceinline__ float bflo(unsigned int w) { return __uint_as_float(w << 16); }
__device__ __forceinline__ float bfhi(unsigned int w) { return __uint_as_float(w & 0xffff0000u); }

__global__ __launch_bounds__(256) void prep_kernel(
    const float* __restrict__ gt, const float* __restrict__ ct,
    const float* __restrict__ W1, const float* __restrict__ b1,
    unsigned short* __restrict__ ws)
{
    int tid = blockIdx.x * 256 + threadIdx.x;
    if (tid < 208) ws[WS_GT + tid] = f2bf(gt[tid]);
    if (tid < 216) ws[WS_CT + tid] = f2bf(ct[tid]);
    if (tid < 24576) {
        int kl  = tid >> 8;     // logical k 0..95
        int col = tid & 255;    // hidden col 0..255
        int chunk = kl >> 3, j = kl & 7;
        int hi, kk;
        if (chunk < 5)        { hi = 0; kk = chunk; }      // guess letters -> half 0
        else if (chunk < 10)  { hi = 1; kk = chunk - 5; }  // constraint letters -> half 1
        else if (chunk == 10) { hi = 0; kk = 5; }          // presence mean -> half 0
        else                  { hi = 1; kk = 5; }          // absent mean  -> half 1
        int s = kk * 2 + hi;                                // physical k-slot 0..11
        ws[WS_W1T + col * 104 + s * 8 + j] = f2bf(W1[kl * 256 + col]);
    } else if (tid < 26624) {
        int idx2 = tid - 24576;
        int col = idx2 >> 3, j = idx2 & 7;                  // slot 12: b1 in j=0
        ws[WS_W1T + col * 104 + 96 + j] = (j == 0) ? f2bf(b1[col]) : (unsigned short)0;
    }
}

// Block = 4 waves over a 64-row tile: wave = (row-group wv>>1, col-half wv&1).
// Each wave: 32 rows x 128 cols, acc[4] = 64 AGPR -> VGPR budget 192 at 2 waves/SIMD.
__global__ __launch_bounds__(256, 2) void wordle_kernel(
    const int* __restrict__ gidx, const int* __restrict__ cidx,
    const int* __restrict__ pidx, const int* __restrict__ plen,
    const int* __restrict__ aidx, const int* __restrict__ alen,
    const float* __restrict__ W2, const float* __restrict__ b2,
    const unsigned short* __restrict__ ws,
    float* __restrict__ out, int tilesPerBlock)
{
    __shared__ unsigned short w1t[26624];   // 52 KB
    __shared__ float outbuf[2][128];        // double-buffered partial sums (1 KB)

    // Stage W1T+b1 (linear coalesced copy; layout pre-applied in d_ws)
    {
        const uint4* src = (const uint4*)(ws + WS_W1T);
        uint4* dst = (uint4*)w1t;
        int tid = threadIdx.x;
        #pragma unroll
        for (int i = 0; i < 13; ++i) dst[tid + i * 256] = src[tid + i * 256];
    }
    __syncthreads();

    const int lane = threadIdx.x & 63;
    const int wv   = threadIdx.x >> 6;
    const int rg   = wv >> 1;               // row group (0: rows 0-31, 1: rows 32-63)
    const int ch   = wv & 1;                // col half  (0: cols 0-127, 1: 128-255)
    const int l31  = lane & 31;
    const int hi   = lane >> 5;
    const unsigned short* gt = ws + WS_GT;
    const unsigned short* ct = ws + WS_CT;
    const unsigned short* tb = hi ? ct : gt;
    const float b2v = b2[0];

    // Constant A-fragment for the b1 slot: lo lanes (1,0,...,0), hi lanes 0.
    short8 a6 = {0, 0, 0, 0, 0, 0, 0, 0};
    a6[0] = hi ? (short)0 : (short)0x3F80;   // bf16 1.0

    // Hoisted epilogue weights (this wave's 4 col-tiles)
    float w2r[4];
    #pragma unroll
    for (int j = 0; j < 4; ++j) w2r[j] = W2[(ch * 4 + j) * 32 + l31];

    // Prefetched per-row indices for the CURRENT tile (scalar loads — aligned)
    int ip0, ip1, ip2, ip3, ip4;
    int s0, s1, s2, s3, s4, s5, s6, s7, s8, s9;
    int lenv;

#define LOADIDX(T) do {                                                     \
        const int r_ = (blockIdx.x * tilesPerBlock + (T)) * 64 + rg * 32 + l31; \
        const int* ip_ = (hi ? cidx : gidx) + r_ * 5;                       \
        ip0 = ip_[0]; ip1 = ip_[1]; ip2 = ip_[2]; ip3 = ip_[3]; ip4 = ip_[4]; \
        const int* si_ = (hi ? aidx : pidx) + r_ * 10;                      \
        s0 = si_[0]; s1 = si_[1]; s2 = si_[2]; s3 = si_[3]; s4 = si_[4];    \
        s5 = si_[5]; s6 = si_[6]; s7 = si_[7]; s8 = si_[8]; s9 = si_[9];    \
        lenv = (hi ? alen : plen)[r_];                                      \
    } while (0)

    LOADIDX(0);

    for (int t = 0; t < tilesPerBlock; ++t) {
        const int tile = blockIdx.x * tilesPerBlock + t;

        // ---------- gather: issue all table loads for this tile ----------
        short8 a0 = *(const short8*)(tb + ip0 * 8);
        short8 a1 = *(const short8*)(tb + ip1 * 8);
        short8 a2 = *(const short8*)(tb + ip2 * 8);
        short8 a3 = *(const short8*)(tb + ip3 * 8);
        short8 a4 = *(const short8*)(tb + ip4 * 8);
        uint4 e0 = *(const uint4*)(gt + s0 * 8);
        uint4 e1 = *(const uint4*)(gt + s1 * 8);
        uint4 e2 = *(const uint4*)(gt + s2 * 8);
        uint4 e3 = *(const uint4*)(gt + s3 * 8);
        uint4 e4 = *(const uint4*)(gt + s4 * 8);
        uint4 e5 = *(const uint4*)(gt + s5 * 8);
        uint4 e6 = *(const uint4*)(gt + s6 * 8);
        uint4 e7 = *(const uint4*)(gt + s7 * 8);
        uint4 e8 = *(const uint4*)(gt + s8 * 8);
        uint4 e9 = *(const uint4*)(gt + s9 * 8);
        const int len = lenv;

        // ---------- prefetch next tile's indices ----------
        if (t + 1 < tilesPerBlock) LOADIDX(t + 1);

        // ---------- MFMAs that don't need a5: b1 slot + kk=0..4 ----------
        // (e-gather L1 latency hides under these ~24 MFMAs)
        f32x16 acc[4];
        #pragma unroll
        for (int j = 0; j < 4; ++j)
            #pragma unroll
            for (int r = 0; r < 16; ++r) acc[j][r] = 0.f;

        #pragma unroll
        for (int j = 0; j < 4; ++j) {
            const int col = (ch * 4 + j) * 32 + l31;
            short8 bv = *(const short8*)(&w1t[col * 104 + 96]);
            acc[j] = __builtin_amdgcn_mfma_f32_32x32x16_bf16(a6, bv, acc[j], 0, 0, 0);
        }
        #pragma unroll
        for (int kk = 0; kk < 5; ++kk) {
            const short8 av = (kk == 0) ? a0 : (kk == 1) ? a1 : (kk == 2) ? a2
                           : (kk == 3) ? a3 : a4;
            const int s = kk * 2 + hi;
            #pragma unroll
            for (int j = 0; j < 4; ++j) {
                const int col = (ch * 4 + j) * 32 + l31;
                short8 bv = *(const short8*)(&w1t[col * 104 + s * 8]);
                acc[j] = __builtin_amdgcn_mfma_f32_32x32x16_bf16(av, bv, acc[j], 0, 0, 0);
            }
        }

        // ---------- masked mean -> a5 (e-loads have long landed) ----------
        short8 a5;
        {
            float m0=0.f,m1=0.f,m2=0.f,m3=0.f,m4=0.f,m5=0.f,m6=0.f,m7=0.f;
            uint4 ev[10] = {e0,e1,e2,e3,e4,e5,e6,e7,e8,e9};
            #pragma unroll
            for (int k = 0; k < 10; ++k) {
                float w = (k < len) ? 1.f : 0.f;
                m0 += w * bflo(ev[k].x); m1 += w * bfhi(ev[k].x);
                m2 += w * bflo(ev[k].y); m3 += w * bfhi(ev[k].y);
                m4 += w * bflo(ev[k].z); m5 += w * bfhi(ev[k].z);
                m6 += w * bflo(ev[k].w); m7 += w * bfhi(ev[k].w);
            }
            const float scl = (len > 0) ? (1.f / (float)len) : 0.f;
            a5[0] = (short)f2bf(m0 * scl); a5[1] = (short)f2bf(m1 * scl);
            a5[2] = (short)f2bf(m2 * scl); a5[3] = (short)f2bf(m3 * scl);
            a5[4] = (short)f2bf(m4 * scl); a5[5] = (short)f2bf(m5 * scl);
            a5[6] = (short)f2bf(m6 * scl); a5[7] = (short)f2bf(m7 * scl);
        }

        // ---------- kk=5 (a5) MFMAs ----------
        #pragma unroll
        for (int j = 0; j < 4; ++j) {
            const int col = (ch * 4 + j) * 32 + l31;
            short8 bv = *(const short8*)(&w1t[col * 104 + (10 + hi) * 8]);
            acc[j] = __builtin_amdgcn_mfma_f32_32x32x16_bf16(a5, bv, acc[j], 0, 0, 0);
        }

        // ---------- epilogue: relu, dot W2 (partial over 128 cols) ----------
        float part[16];
        #pragma unroll
        for (int r = 0; r < 16; ++r) part[r] = 0.f;
        #pragma unroll
        for (int j = 0; j < 4; ++j) {
            #pragma unroll
            for (int r = 0; r < 16; ++r) {
                float h = acc[j][r];
                h = h > 0.f ? h : 0.f;
                part[r] += h * w2r[j];
            }
        }

        // ---------- split-register butterfly reduce over 32 lanes ----------
        const int b_ = (l31 >> 4) & 1, c_ = (l31 >> 3) & 1,
                  d_ = (l31 >> 2) & 1, e_ = (l31 >> 1) & 1;
        float p1[8], p2[4], p3[2], p4, p5;
        #pragma unroll
        for (int i = 0; i < 8; ++i) {
            float keep = b_ ? part[8 + i] : part[i];
            float send = b_ ? part[i]     : part[8 + i];
            p1[i] = keep + __shfl_xor(send, 16, 64);
        }
        #pragma unroll
        for (int i = 0; i < 4; ++i) {
            float keep = c_ ? p1[4 + i] : p1[i];
            float send = c_ ? p1[i]     : p1[4 + i];
            p2[i] = keep + __shfl_xor(send, 8, 64);
        }
        #pragma unroll
        for (int i = 0; i < 2; ++i) {
            float keep = d_ ? p2[2 + i] : p2[i];
            float send = d_ ? p2[i]     : p2[2 + i];
            p3[i] = keep + __shfl_xor(send, 4, 64);
        }
        {
            float keep = e_ ? p3[1] : p3[0];
            float send = e_ ? p3[0] : p3[1];
            p4 = keep + __shfl_xor(send, 2, 64);
        }
        p5 = p4 + __shfl_xor(p4, 1, 64);
        // even lane l31 holds this wave's partial for r = l31>>1
        // (row-in-group = (r&3)+8*(r>>2)+4*hi)

        // ---------- combine col-halves via double-buffered LDS ----------
        if (!(lane & 1)) {
            const int r = l31 >> 1;
            outbuf[t & 1][ch * 64 + rg * 32 + 4 * hi + (r & 3) + 8 * (r >> 2)] = p5;
        }
        __syncthreads();
        if (threadIdx.x < 64) {
            out[tile * 64 + threadIdx.x] =
                outbuf[t & 1][threadIdx.x] + outbuf[t & 1][64 + threadIdx.x] + b2v;
        }
        // no trailing barrier: next tile writes the other outbuf buffer
    }
#undef LOADIDX
}

extern "C" void kernel_launch(void* const* d_in, const int* in_sizes, int n_in,
                              void* d_out, int out_size, void* d_ws, size_t ws_size,
                              hipStream_t stream) {
    const int*   gidx = (const int*)d_in[0];
    const int*   cidx = (const int*)d_in[1];
    const int*   pidx = (const int*)d_in[2];
    const int*   plen = (const int*)d_in[3];
    const int*   aidx = (const int*)d_in[4];
    const int*   alen = (const int*)d_in[5];
    const float* gt   = (const float*)d_in[6];
    const float* ct   = (const float*)d_in[7];
    const float* W1   = (const float*)d_in[8];
    const float* b1   = (const float*)d_in[9];
    const float* W2   = (const float*)d_in[10];
    const float* b2   = (const float*)d_in[11];
    float* out = (float*)d_out;
    unsigned short* ws = (unsigned short*)d_ws;

    const int B = in_sizes[0] / 5;          // 1048576
    prep_kernel<<<104, 256, 0, stream>>>(gt, ct, W1, b1, ws);

    const int tilesTotal = B / 64;          // 16384 block-tiles of 64 rows
    int tpb = 32;                           // 512 persistent blocks = 2/CU
    while (tpb > 1 && (tilesTotal % tpb)) tpb >>= 1;
    const int blocks = tilesTotal / tpb;
    wordle_kernel<<<blocks, 256, 0, stream>>>(gidx, cidx, pidx, plen, aidx, alen,
                                              W2, b2, ws, out, tpb);
}

// Round 12
// 76.599 us; speedup vs baseline: 1.3712x; 1.3712x over previous
//
#include <hip/hip_runtime.h>

typedef __attribute__((ext_vector_type(8))) short short8;
typedef __attribute__((ext_vector_type(16))) float f32x16;
typedef __attribute__((ext_vector_type(2))) float f32x2;

// d_ws layout (ushort elements):
#define WS_GT   0        // 26*8 = 208 bf16
#define WS_CT   256      // 27*8 = 216 bf16
#define WS_W1T  512      // 256 cols * 13 slots * 8 bf16 = 26624 ushorts (52 KB)
                         // slots 0-11: W1T data (s = kk*2 + hi); slot 12: pad

__device__ __forceinline__ unsigned short f2bf(float f) {
    unsigned int u = __float_as_uint(f);
    u = (u + 0x7fffu + ((u >> 16) & 1u)) >> 16;   // RNE
    return (unsigned short)u;
}
__device__ __forceinline__ float bflo(unsigned int w) { return __uint_as_float(w << 16); }
__device__ __forceinline__ float bfhi(unsigned int w) { return __uint_as_float(w & 0xffff0000u); }

// W1 stored transposed [col][13 slots of 8]; 208 B col stride (odd multiple of
// 16 B -> ds_read_b128 conflict-free, verified rounds 5-7/9: 0 conflicts).
__global__ __launch_bounds__(256) void prep_kernel(
    const float* __restrict__ gt, const float* __restrict__ ct,
    const float* __restrict__ W1, unsigned short* __restrict__ ws)
{
    int tid = blockIdx.x * 256 + threadIdx.x;
    if (tid < 208) ws[WS_GT + tid] = f2bf(gt[tid]);
    if (tid < 216) ws[WS_CT + tid] = f2bf(ct[tid]);
    if (tid < 24576) {
        int kl  = tid >> 8;     // logical k 0..95
        int col = tid & 255;    // hidden col 0..255
        int chunk = kl >> 3, j = kl & 7;
        int hi, kk;
        if (chunk < 5)        { hi = 0; kk = chunk; }      // guess letters -> half 0
        else if (chunk < 10)  { hi = 1; kk = chunk - 5; }  // constraint letters -> half 1
        else if (chunk == 10) { hi = 0; kk = 5; }          // presence mean -> half 0
        else                  { hi = 1; kk = 5; }          // absent mean  -> half 1
        int s = kk * 2 + hi;                                // physical k-slot 0..11
        ws[WS_W1T + col * 104 + s * 8 + j] = f2bf(W1[kl * 256 + col]);
    }
}

__global__ __launch_bounds__(256, 2) void wordle_kernel(
    const int* __restrict__ gidx, const int* __restrict__ cidx,
    const int* __restrict__ pidx, const int* __restrict__ plen,
    const int* __restrict__ aidx, const int* __restrict__ alen,
    const float* __restrict__ b1, const float* __restrict__ W2,
    const float* __restrict__ b2, const unsigned short* __restrict__ ws,
    float* __restrict__ out, int tilesPerBlock)
{
    __shared__ unsigned short w1t[26624];   // 52 KB
    __shared__ float outbuf[128];           // 4 waves * 32 rows

    // Stage W1T (linear coalesced copy; layout pre-applied in d_ws)
    {
        const uint4* src = (const uint4*)(ws + WS_W1T);
        uint4* dst = (uint4*)w1t;
        int tid = threadIdx.x;
        #pragma unroll
        for (int i = 0; i < 13; ++i) dst[tid + i * 256] = src[tid + i * 256];
    }
    __syncthreads();

    const int lane = threadIdx.x & 63;
    const int wv   = threadIdx.x >> 6;
    const int l31  = lane & 31;
    const int hi   = lane >> 5;
    const unsigned short* gt = ws + WS_GT;
    const unsigned short* ct = ws + WS_CT;
    const unsigned short* tb = hi ? ct : gt;
    const float b2v = b2[0];

    // Hoisted epilogue weights (8 col-tiles of 32)
    float w2r[8], b1r[8];
    #pragma unroll
    for (int nt = 0; nt < 8; ++nt) {
        w2r[nt] = W2[nt * 32 + l31];
        b1r[nt] = b1[nt * 32 + l31];
    }

    // Prefetched per-row indices for the CURRENT tile (scalar loads — aligned)
    int ip0, ip1, ip2, ip3, ip4;
    int s0, s1, s2, s3, s4, s5, s6, s7, s8, s9;
    int lenv;

#define LOADIDX(T) do {                                                     \
        const int r_ = (blockIdx.x * tilesPerBlock + (T)) * 128 + wv * 32 + l31; \
        const int* ip_ = (hi ? cidx : gidx) + r_ * 5;                       \
        ip0 = ip_[0]; ip1 = ip_[1]; ip2 = ip_[2]; ip3 = ip_[3]; ip4 = ip_[4]; \
        const int* si_ = (hi ? aidx : pidx) + r_ * 10;                      \
        s0 = si_[0]; s1 = si_[1]; s2 = si_[2]; s3 = si_[3]; s4 = si_[4];    \
        s5 = si_[5]; s6 = si_[6]; s7 = si_[7]; s8 = si_[8]; s9 = si_[9];    \
        lenv = (hi ? alen : plen)[r_];                                      \
    } while (0)

    LOADIDX(0);

    for (int t = 0; t < tilesPerBlock; ++t) {
        const int tile = blockIdx.x * tilesPerBlock + t;

        // ---------- gather: issue all table loads for this tile ----------
        short8 a0 = *(const short8*)(tb + ip0 * 8);
        short8 a1 = *(const short8*)(tb + ip1 * 8);
        short8 a2 = *(const short8*)(tb + ip2 * 8);
        short8 a3 = *(const short8*)(tb + ip3 * 8);
        short8 a4 = *(const short8*)(tb + ip4 * 8);
        uint4 e0 = *(const uint4*)(gt + s0 * 8);
        uint4 e1 = *(const uint4*)(gt + s1 * 8);
        uint4 e2 = *(const uint4*)(gt + s2 * 8);
        uint4 e3 = *(const uint4*)(gt + s3 * 8);
        uint4 e4 = *(const uint4*)(gt + s4 * 8);
        uint4 e5 = *(const uint4*)(gt + s5 * 8);
        uint4 e6 = *(const uint4*)(gt + s6 * 8);
        uint4 e7 = *(const uint4*)(gt + s7 * 8);
        uint4 e8 = *(const uint4*)(gt + s8 * 8);
        uint4 e9 = *(const uint4*)(gt + s9 * 8);
        const int len = lenv;

        // ---------- prefetch next tile's indices (hides under MFMA) ----------
        if (t + 1 < tilesPerBlock) LOADIDX(t + 1);

        // ---------- masked mean -> a5 (packed f32 pairs) ----------
        short8 a5;
        {
            f32x2 m0 = {0.f, 0.f}, m1 = {0.f, 0.f}, m2 = {0.f, 0.f}, m3 = {0.f, 0.f};
            uint4 ev[10] = {e0,e1,e2,e3,e4,e5,e6,e7,e8,e9};
            #pragma unroll
            for (int k = 0; k < 10; ++k) {
                const float w = (k < len) ? 1.f : 0.f;
                const f32x2 wv2 = {w, w};
                f32x2 v0 = {bflo(ev[k].x), bfhi(ev[k].x)};
                f32x2 v1 = {bflo(ev[k].y), bfhi(ev[k].y)};
                f32x2 v2 = {bflo(ev[k].z), bfhi(ev[k].z)};
                f32x2 v3 = {bflo(ev[k].w), bfhi(ev[k].w)};
                m0 += wv2 * v0; m1 += wv2 * v1; m2 += wv2 * v2; m3 += wv2 * v3;
            }
            const float scl = (len > 0) ? (1.f / (float)len) : 0.f;
            a5[0] = (short)f2bf(m0[0] * scl); a5[1] = (short)f2bf(m0[1] * scl);
            a5[2] = (short)f2bf(m1[0] * scl); a5[3] = (short)f2bf(m1[1] * scl);
            a5[4] = (short)f2bf(m2[0] * scl); a5[5] = (short)f2bf(m2[1] * scl);
            a5[6] = (short)f2bf(m3[0] * scl); a5[7] = (short)f2bf(m3[1] * scl);
        }

        // ---------- MFMA: 32 rows x 256 cols, K=96, single pass acc[8] ----------
        f32x16 acc[8];
        #pragma unroll
        for (int nt = 0; nt < 8; ++nt)
            #pragma unroll
            for (int r = 0; r < 16; ++r) acc[nt][r] = 0.f;

        #pragma unroll
        for (int kk = 0; kk < 6; ++kk) {
            const short8 av = (kk == 0) ? a0 : (kk == 1) ? a1 : (kk == 2) ? a2
                           : (kk == 3) ? a3 : (kk == 4) ? a4 : a5;
            const int s = kk * 2 + hi;
            #pragma unroll
            for (int nt = 0; nt < 8; ++nt) {
                const int col = nt * 32 + l31;
                short8 bv = *(const short8*)(&w1t[col * 104 + s * 8]);
                acc[nt] = __builtin_amdgcn_mfma_f32_32x32x16_bf16(av, bv, acc[nt], 0, 0, 0);
            }
        }

        // ---------- epilogue: b1-add + relu + W2-dot, packed f32 pairs ----------
        f32x2 part2[8];
        #pragma unroll
        for (int i = 0; i < 8; ++i) { part2[i][0] = 0.f; part2[i][1] = 0.f; }
        #pragma unroll
        for (int nt = 0; nt < 8; ++nt) {
            const f32x2 w2v = {w2r[nt], w2r[nt]};
            const f32x2 b1v = {b1r[nt], b1r[nt]};
            const f32x2 z = {0.f, 0.f};
            #pragma unroll
            for (int i = 0; i < 8; ++i) {
                f32x2 h = {acc[nt][2 * i], acc[nt][2 * i + 1]};
                h = __builtin_elementwise_max(h + b1v, z);
                part2[i] += h * w2v;
            }
        }

        // ---------- split-register butterfly reduce over 32 lanes ----------
        // (operates on float2 pairs; element r = part2[r>>1][r&1])
        const int b_ = (l31 >> 4) & 1, c_ = (l31 >> 3) & 1,
                  d_ = (l31 >> 2) & 1, e_ = (l31 >> 1) & 1;
        f32x2 q1[4], q2[2], q3;
        float p4, p5;
        #pragma unroll
        for (int i = 0; i < 4; ++i) {          // exchange r<8 vs r>=8
            f32x2 keep = b_ ? part2[4 + i] : part2[i];
            f32x2 send = b_ ? part2[i]     : part2[4 + i];
            f32x2 got;
            got[0] = __shfl_xor(send[0], 16, 64);
            got[1] = __shfl_xor(send[1], 16, 64);
            q1[i] = keep + got;
        }
        #pragma unroll
        for (int i = 0; i < 2; ++i) {          // exchange r<4 vs r>=4
            f32x2 keep = c_ ? q1[2 + i] : q1[i];
            f32x2 send = c_ ? q1[i]     : q1[2 + i];
            f32x2 got;
            got[0] = __shfl_xor(send[0], 8, 64);
            got[1] = __shfl_xor(send[1], 8, 64);
            q2[i] = keep + got;
        }
        {                                       // exchange r<2 vs r>=2
            f32x2 keep = d_ ? q2[1] : q2[0];
            f32x2 send = d_ ? q2[0] : q2[1];
            f32x2 got;
            got[0] = __shfl_xor(send[0], 4, 64);
            got[1] = __shfl_xor(send[1], 4, 64);
            q3 = keep + got;
        }
        {                                       // exchange r=0 vs r=1 (inside float2)
            float keep = e_ ? q3[1] : q3[0];
            float send = e_ ? q3[0] : q3[1];
            p4 = keep + __shfl_xor(send, 2, 64);
        }
        p5 = p4 + __shfl_xor(p4, 1, 64);
        // even lane l31 holds the full sum for r = l31>>1 (row = (r&3)+8*(r>>2)+4*hi)

        // ---------- coalesced store via LDS transpose (512 B staging) ----------
        if (!(lane & 1)) {
            const int r = l31 >> 1;
            outbuf[wv * 32 + 4 * hi + (r & 3) + 8 * (r >> 2)] = p5 + b2v;
        }
        asm volatile("s_waitcnt lgkmcnt(0)" ::: "memory");
        if (lane < 32) {
            out[tile * 128 + wv * 32 + lane] = outbuf[wv * 32 + lane];
        }
    }
#undef LOADIDX
}

extern "C" void kernel_launch(void* const* d_in, const int* in_sizes, int n_in,
                              void* d_out, int out_size, void* d_ws, size_t ws_size,
                              hipStream_t stream) {
    const int*   gidx = (const int*)d_in[0];
    const int*   cidx = (const int*)d_in[1];
    const int*   pidx = (const int*)d_in[2];
    const int*   plen = (const int*)d_in[3];
    const int*   aidx = (const int*)d_in[4];
    const int*   alen = (const int*)d_in[5];
    const float* gt   = (const float*)d_in[6];
    const float* ct   = (const float*)d_in[7];
    const float* W1   = (const float*)d_in[8];
    const float* b1   = (const float*)d_in[9];
    const float* W2   = (const float*)d_in[10];
    const float* b2   = (const float*)d_in[11];
    float* out = (float*)d_out;
    unsigned short* ws = (unsigned short*)d_ws;

    const int B = in_sizes[0] / 5;          // 1048576
    prep_kernel<<<96, 256, 0, stream>>>(gt, ct, W1, ws);

    const int tilesTotal = B / 128;         // 8192 block-tiles of 128 rows
    int tpb = 16;                           // 512 persistent blocks = 2/CU
    while (tpb > 1 && (tilesTotal % tpb)) tpb >>= 1;
    const int blocks = tilesTotal / tpb;
    wordle_kernel<<<blocks, 256, 0, stream>>>(gidx, cidx, pidx, plen, aidx, alen,
                                              b1, W2, b2, ws, out, tpb);
}